// Round 9
// baseline (551.916 us; speedup 1.0000x reference)
//
#include <hip/hip_runtime.h>
#include <hip/hip_fp16.h>
#include <cstdint>
#include <cstring>

// VQR circuit simulator: 16 qubits, B=512, 4 layers.
// CNOTs are GF(2) index-relabeling bookkeeping. Fused 1q gates (SU(2)) are
// XOR-mask pair rotations, scheduled into 2 window passes
// (gen+gates+store, load+gates+measure). Within a pass, bundles of <=4
// SAME-LAYER mask-independent gates (same-layer => pairwise Pauli parity 0
// => flip==0 => per-gate-uniform sign): each thread applies a bundle on a
// dim-4 coset (16 amps) held as PACKED v2f (re,im) registers, doing complex
// math directly on packed values: x*P = xr*P + {-xi,xi}*swap(P) -> 8
// v_pk_fma_f32 per pair, constants hoisted per gate. Dirty bundles (rare,
// tail pads only) take the proven scalar path. AoS LDS (low conflicts).

typedef float v2f __attribute__((ext_vector_type(2)));

struct BundleMeta {
    uint16_t voff[16];   // coset offsets (local 12-bit index space)
    uint16_t row[4];     // branch parity masks (local bits), per slot
    uint16_t flip[4];    // flip[g] bit t = parity(voff[t] & row[g]); 0 => packed path
    uint8_t  piv[4];     // pivot bit positions, ASCENDING (rep expansion)
    uint8_t  gidx[4];    // gate coefficient index l*16+w; 0xFF = identity pad
    uint8_t  nl[4];      // branch parity masks over the 4 chunk bits
};

struct PassMeta {
    int       nbundles;
    BundleMeta bd[24];
    uint8_t   gap[4];          // non-local bit positions, ASCENDING (all >=8)
    uint8_t   nlw[4];          // chunk bit k -> wire
    uint8_t   wire_of_bit[12]; // packed LDS bit -> wire (product-state init)
    uint16_t  meas_row;        // measurement parity mask (local bits)
    uint8_t   meas_nl;         // measurement parity mask (chunk bits)
};

__device__ __forceinline__ float2 cmul2(float2 a, float2 b) {
    return make_float2(a.x * b.x - a.y * b.y, a.x * b.y + a.y * b.x);
}
__device__ __forceinline__ float xorf(float a, unsigned s) {
    return __uint_as_float(__float_as_uint(a) ^ s);
}

// MODE 0: coef + product state + gates + store (fp16)
// MODE 1: coef + load + gates + store (in-place, fp16)
// MODE 2: coef + load + gates + measurement reduce (no store)
template <int MODE>
__global__ __launch_bounds__(256, 4)
void pass_kernel(const float* __restrict__ X, const float* __restrict__ Wt,
                 const float* __restrict__ Bs, __half2* __restrict__ state,
                 float* __restrict__ out, PassMeta meta)
{
    __shared__ v2f    amp[4096];   // 32 KiB, AoS (re,im) per amp
    __shared__ float4 coef[64];    // 1 KiB  (SU(2) (a,b) per gate)
    const int tid = threadIdx.x;
    const int bb  = blockIdx.x >> 4;
    const unsigned c = blockIdx.x & 15u;
    const size_t base = (size_t)bb << 16;

    // ---- in-block coefficients: U = Rz(t2)Ry(t1)Rz(t0)Rx(2atan x), SU(2) (a,b)
    if (tid < 64) {
        int l = tid >> 4, w = tid & 15;
        float x  = X[bb * 16 + w];
        float ce = 1.0f / sqrtf(1.0f + x * x);
        float se = x * ce;
        float t0 = 0.5f * Wt[(l * 16 + w) * 3 + 0];
        float t1 = 0.5f * Wt[(l * 16 + w) * 3 + 1];
        float t2 = 0.5f * Wt[(l * 16 + w) * 3 + 2];
        float c1 = cosf(t1), s1 = sinf(t1);
        float ca = cosf(t0 + t2), sa = sinf(t0 + t2);
        float cb = cosf(t2 - t0), sb = sinf(t2 - t0);
        float2 W00 = make_float2( c1 * ca, -c1 * sa);
        float2 W01 = make_float2(-s1 * cb,  s1 * sb);
        float2 a  = make_float2(W00.x * ce + W01.y * se, W00.y * ce - W01.x * se);
        float2 b2 = make_float2(W00.y * se + W01.x * ce, -W00.x * se + W01.y * ce);
        coef[tid] = make_float4(a.x, a.y, b2.x, b2.y);
    }
    if (MODE == 0 && c == 0 && tid == 64) out[bb] = Bs[0];  // bias init

    auto expand = [&](unsigned x) -> unsigned {   // gaps ascending, all >= 8
        #pragma unroll
        for (int k = 0; k < 4; ++k) {
            unsigned g = meta.gap[k];
            x = ((x >> g) << (g + 1)) | (x & ((1u << g) - 1u)) | (((c >> k) & 1u) << g);
        }
        return x;
    };

    if constexpr (MODE == 0) {
        __syncthreads();   // coef ready
        if (tid == 0) {
            float2 k = make_float2(1.f, 0.f);
            #pragma unroll
            for (int t = 0; t < 4; ++t) {
                float4 u = coef[meta.nlw[t]];
                float2 col = ((c >> t) & 1u) ? make_float2(-u.z, u.w)
                                             : make_float2(u.x, u.y);
                k = cmul2(k, col);
            }
            amp[0] = v2f{k.x, k.y};
        }
        __syncthreads();
        for (int s = 0; s < 12; ++s) {
            const int n = 1 << s;
            float4 u = coef[meta.wire_of_bit[s]];
            const float2 c0 = make_float2(u.x, u.y);
            const float2 c1 = make_float2(-u.z, u.w);
            for (int i = tid; i < n; i += 256) {
                float2 a = make_float2(amp[i].x, amp[i].y);
                float2 h = cmul2(a, c1);
                float2 l = cmul2(a, c0);
                amp[i + n] = v2f{h.x, h.y};
                amp[i]     = v2f{l.x, l.y};
            }
            __syncthreads();
        }
    } else {
        #pragma unroll
        for (int it = 0; it < 4; ++it) {
            unsigned u = (unsigned)(tid + it * 256) * 4u;
            unsigned a = expand(u);
            uint4 v = *reinterpret_cast<const uint4*>(state + base + a);
            float2 f0 = __half22float2(__builtin_bit_cast(__half2, v.x));
            float2 f1 = __half22float2(__builtin_bit_cast(__half2, v.y));
            float2 f2 = __half22float2(__builtin_bit_cast(__half2, v.z));
            float2 f3 = __half22float2(__builtin_bit_cast(__half2, v.w));
            amp[u + 0] = v2f{f0.x, f0.y};
            amp[u + 1] = v2f{f1.x, f1.y};
            amp[u + 2] = v2f{f2.x, f2.y};
            amp[u + 3] = v2f{f3.x, f3.y};
        }
        __syncthreads();   // also covers coef staging
    }

    for (int ci = 0; ci < meta.nbundles; ++ci) {
        const BundleMeta& B = meta.bd[ci];
        unsigned r = (unsigned)tid;
        #pragma unroll
        for (int k = 0; k < 4; ++k) {
            unsigned p = B.piv[k];
            r = ((r >> p) << (p + 1)) | (r & ((1u << p) - 1u));
        }
        v2f a[16];
        #pragma unroll
        for (int t = 0; t < 16; ++t) a[t] = amp[r ^ B.voff[t]];
        #pragma unroll
        for (int g = 0; g < 4; ++g) {
            if (B.gidx[g] == 0xFF) continue;       // identity pad (uniform skip)
            const float4 uv = coef[B.gidx[g]];
            const unsigned sb31 =
                ((unsigned)((__popc(r & (unsigned)B.row[g]) +
                             __popc((unsigned)B.nl[g] & c)) & 1)) << 31;
            const float ai_s = xorf(uv.y, sb31);
            const float br_s = xorf(uv.z, sb31);
            if (B.flip[g] == 0) {
                // packed path: amps stay (re,im)-packed; per-gate constants.
                // x*P = xr*P + {-xi,xi}*swap(P)
                const float AR = uv.x;
                const v2f V1 = { xorf(ai_s, 0x80000000u), ai_s };  // (-ai_s, ai_s)
                const v2f V2 = { xorf(uv.w, 0x80000000u), uv.w };  // (-bi, bi)
                #pragma unroll
                for (int k = 0; k < 8; ++k) {
                    const int t  = ((k >> g) << (g + 1)) | (k & ((1 << g) - 1));
                    const int t2 = t | (1 << g);
                    const v2f P = a[t], Q = a[t2];
                    const v2f Psw = __builtin_shufflevector(P, P, 1, 0);
                    const v2f Qsw = __builtin_shufflevector(Q, Q, 1, 0);
                    v2f np = AR * P + V1 * Psw + br_s * Q + V2 * Qsw;
                    v2f nq = AR * Q - V1 * Qsw - br_s * P + V2 * Psw;
                    a[t] = np; a[t2] = nq;
                }
            } else {
                // scalar fallback (dirty pads only): r6-proven math with flip.
                const unsigned fl = B.flip[g];
                #pragma unroll
                for (int t = 0; t < 16; ++t) {
                    if (t & (1 << g)) continue;
                    const int t2 = t | (1 << g);
                    const unsigned fb = (fl << (31 - t)) & 0x80000000u;
                    const float tai = xorf(ai_s, fb);
                    const float tbr = xorf(br_s, fb);
                    const float pr = a[t].x,  pi = a[t].y;
                    const float qr = a[t2].x, qi = a[t2].y;
                    const float npr = __builtin_fmaf(uv.x, pr,
                                      __builtin_fmaf(-tai, pi,
                                      __builtin_fmaf(tbr, qr, -uv.w * qi)));
                    const float npi = __builtin_fmaf(uv.x, pi,
                                      __builtin_fmaf( tai, pr,
                                      __builtin_fmaf(tbr, qi,  uv.w * qr)));
                    const float nqr = __builtin_fmaf(-tbr, pr,
                                      __builtin_fmaf(-uv.w, pi,
                                      __builtin_fmaf(uv.x, qr,  tai * qi)));
                    const float nqi = __builtin_fmaf(-tbr, pi,
                                      __builtin_fmaf( uv.w, pr,
                                      __builtin_fmaf(uv.x, qi, -tai * qr)));
                    a[t]  = v2f{npr, npi};
                    a[t2] = v2f{nqr, nqi};
                }
            }
        }
        if (MODE == 2 && ci == meta.nbundles - 1) {
            // measure directly from registers (skip final LDS round-trip)
            float acc = 0.f;
            const unsigned mcp = (unsigned)(__popc((unsigned)meta.meas_nl & c) & 1);
            #pragma unroll
            for (int t = 0; t < 16; ++t) {
                float pr = __builtin_fmaf(a[t].x, a[t].x, a[t].y * a[t].y);
                unsigned sg = ((unsigned)__popc((r ^ B.voff[t]) &
                               (unsigned)meta.meas_row) & 1u) ^ mcp;
                acc += sg ? -pr : pr;
            }
            for (int off = 32; off > 0; off >>= 1) acc += __shfl_down(acc, off, 64);
            if ((tid & 63) == 0) atomicAdd(&out[bb], acc);
            return;
        }
        #pragma unroll
        for (int t = 0; t < 16; ++t) amp[r ^ B.voff[t]] = a[t];
        __syncthreads();
    }

    if constexpr (MODE == 2) {
        // fallback (only if nbundles==0): measure from LDS
        float acc = 0.f;
        const unsigned mcp = (unsigned)(__popc((unsigned)meta.meas_nl & c) & 1);
        for (int k = 0; k < 16; ++k) {
            unsigned u = (unsigned)(tid + k * 256);
            v2f a = amp[u];
            float pr = a.x * a.x + a.y * a.y;
            acc += (((unsigned)__popc(u & (unsigned)meta.meas_row) & 1u) ^ mcp)
                 ? -pr : pr;
        }
        for (int off = 32; off > 0; off >>= 1) acc += __shfl_down(acc, off, 64);
        if ((tid & 63) == 0) atomicAdd(&out[bb], acc);
    } else {
        #pragma unroll
        for (int it = 0; it < 4; ++it) {
            unsigned u = (unsigned)(tid + it * 256) * 4u;
            unsigned ad = expand(u);
            __half2 h0 = __float22half2_rn(make_float2(amp[u + 0].x, amp[u + 0].y));
            __half2 h1 = __float22half2_rn(make_float2(amp[u + 1].x, amp[u + 1].y));
            __half2 h2 = __float22half2_rn(make_float2(amp[u + 2].x, amp[u + 2].y));
            __half2 h3 = __float22half2_rn(make_float2(amp[u + 3].x, amp[u + 3].y));
            uint4 v;
            v.x = __builtin_bit_cast(unsigned, h0);
            v.y = __builtin_bit_cast(unsigned, h1);
            v.z = __builtin_bit_cast(unsigned, h2);
            v.w = __builtin_bit_cast(unsigned, h3);
            *reinterpret_cast<uint4*>(state + base + ad) = v;
        }
    }
}

extern "C" void kernel_launch(void* const* d_in, const int* in_sizes, int n_in,
                              void* d_out, int out_size, void* d_ws, size_t ws_size,
                              hipStream_t stream)
{
    const float* X  = (const float*)d_in[0];
    const float* Wt = (const float*)d_in[1];
    const float* Bs = (const float*)d_in[2];
    float* out = (float*)d_out;
    __half2* state = (__half2*)d_ws;

    int group = 1;   // fp16 state: 256 KiB per batch element
    while (group < 512 && (size_t)(group * 2) * (65536ull * 4) <= ws_size)
        group <<= 1;
    const int ngroups = 512 / group;

    // ---- GF(2) bookkeeping (sequential CNOT ring, matches reference) ----
    uint16_t D[16], R[16];
    for (int w = 0; w < 16; ++w) { D[w] = R[w] = (uint16_t)(1u << w); }
    struct G { uint16_t D, R; uint8_t gidx; bool kept; bool sched; };
    G gl[48]; int ng = 0;
    for (int l = 1; l <= 3; ++l) {
        for (int w = 0; w < 16; ++w) { int t = (w + 1) & 15; D[w] ^= D[t]; R[t] ^= R[w]; }
        for (int w = 0; w < 16; ++w)
            gl[ng++] = G{D[w], R[w], (uint8_t)(l * 16 + w), true, false};
    }
    for (int w = 0; w < 16; ++w) { int t = (w + 1) & 15; D[w] ^= D[t]; R[t] ^= R[w]; }
    const uint16_t Rmeas = R[0];

    // Backward prune
    {
        uint16_t keptD[49], keptR[49]; int nk = 0;
        keptD[nk] = 0; keptR[nk] = Rmeas; ++nk;
        for (int i = ng - 1; i >= 0; --i) {
            bool comm = true;
            for (int k = 0; k < nk; ++k) {
                if (__builtin_parity((unsigned)(gl[i].D & keptR[k])) ||
                    __builtin_parity((unsigned)(keptD[k] & gl[i].R))) { comm = false; break; }
            }
            if (comm) gl[i].kept = false;
            else { keptD[nk] = gl[i].D; keptR[nk] = gl[i].R; ++nk; }
        }
    }
    int nkept = 0;
    for (int i = 0; i < ng; ++i) if (gl[i].kept) ++nkept;

    auto commute = [&](int i, int j) -> bool {
        return !(__builtin_parity((unsigned)(gl[i].D & gl[j].R)) ||
                 __builtin_parity((unsigned)(gl[j].D & gl[i].R)));
    };

    const int MAXP = 8;
    auto simulate = [&](uint16_t SA, uint16_t SB, int* passOf) -> int {
        for (int i = 0; i < ng; ++i) gl[i].sched = false;
        int rem = nkept, np = 0, stall = 0;
        while (rem > 0 && np < MAXP) {
            uint16_t S = (np & 1) ? SB : SA;
            int got = 0;
            for (int i = 0; i < ng; ++i) {
                if (!gl[i].kept || gl[i].sched) continue;
                if (gl[i].D & S) continue;
                bool ok = true;
                for (int j = 0; j < i; ++j) {
                    if (!gl[j].kept || gl[j].sched) continue;
                    if (!commute(i, j)) { ok = false; break; }
                }
                if (!ok) continue;
                gl[i].sched = true; --rem; ++got;
                if (passOf) passOf[i] = np;
            }
            ++np;
            if (got == 0) { if (++stall >= 2) break; } else stall = 0;
        }
        return rem == 0 ? np : 99;
    };

    // Window-pair search (4 excluded wires per window, consecutive runs)
    int bestNp = 99, bestA = 0, bestB = 8;
    for (int a = 0; a < 16; ++a) {
        for (int b = 0; b < 16; ++b) {
            uint16_t SA = 0, SB = 0;
            for (int k = 0; k < 4; ++k) {
                SA |= (uint16_t)(1u << ((a + k) & 15));
                SB |= (uint16_t)(1u << ((b + k) & 15));
            }
            int np = simulate(SA, SB, nullptr);
            if (np < bestNp) { bestNp = np; bestA = a; bestB = b; }
        }
    }
    uint16_t SA = 0, SB = 0;
    int exA[4], exB[4];
    for (int k = 0; k < 4; ++k) {
        exA[k] = (bestA + k) & 15; exB[k] = (bestB + k) & 15;
        SA |= (uint16_t)(1u << exA[k]); SB |= (uint16_t)(1u << exB[k]);
    }
    int passOf[48];
    for (int i = 0; i < ng; ++i) passOf[i] = -1;
    int np = simulate(SA, SB, passOf);
    if (np > MAXP) np = MAXP;
    if (np < 2) np = 2;

    // Wire -> bit position: all excluded wires at positions >= 8.
    int wireToPos[16]; bool used[16] = {};
    int pos = 15;
    for (int k = 0; k < 4; ++k) { wireToPos[exA[k]] = pos--; used[exA[k]] = true; }
    for (int k = 0; k < 4; ++k)
        if (!used[exB[k]]) { wireToPos[exB[k]] = pos--; used[exB[k]] = true; }
    for (int w = 0; w < 16; ++w) if (!used[w]) wireToPos[w] = pos--;
    int posToWire[16];
    for (int w = 0; w < 16; ++w) posToWire[wireToPos[w]] = w;

    PassMeta pms[8];
    for (int p = 0; p < np; ++p) {
        PassMeta& M = pms[p];
        memset(&M, 0, sizeof(M));
        const int* ex = (p & 1) ? exB : exA;
        int gp[4], gw[4];
        for (int k = 0; k < 4; ++k) { gp[k] = wireToPos[ex[k]]; gw[k] = ex[k]; }
        for (int a2 = 0; a2 < 4; ++a2)
            for (int b2 = a2 + 1; b2 < 4; ++b2)
                if (gp[b2] < gp[a2]) {
                    int t = gp[a2]; gp[a2] = gp[b2]; gp[b2] = t;
                    t = gw[a2]; gw[a2] = gw[b2]; gw[b2] = t;
                }
        for (int k = 0; k < 4; ++k) { M.gap[k] = (uint8_t)gp[k]; M.nlw[k] = (uint8_t)gw[k]; }
        int packedOfWire[16];
        for (int w = 0; w < 16; ++w) packedOfWire[w] = -1;
        int t = 0;
        for (int q = 0; q < 16; ++q) {
            bool isgap = false;
            for (int k = 0; k < 4; ++k) if (q == gp[k]) isgap = true;
            if (isgap) continue;
            M.wire_of_bit[t] = (uint8_t)posToWire[q];
            packedOfWire[posToWire[q]] = t;
            ++t;
        }
        // local gate list (schedule order; layer-major)
        struct LG { uint16_t m, r; uint8_t nl, gidx; };
        LG ls[48]; int nsel = 0;
        for (int i = 0; i < ng; ++i) {
            if (!gl[i].kept || passOf[i] != p) continue;
            uint16_t m = 0, r = 0; uint8_t nl = 0;
            for (int w = 0; w < 16; ++w) {
                if ((gl[i].D >> w) & 1) m |= (uint16_t)(1u << packedOfWire[w]);
                if (((gl[i].R >> w) & 1) && packedOfWire[w] >= 0)
                    r |= (uint16_t)(1u << packedOfWire[w]);
            }
            for (int k = 0; k < 4; ++k)
                if ((gl[i].R >> gw[k]) & 1) nl |= (uint8_t)(1u << k);
            ls[nsel++] = LG{m, r, nl, gl[i].gidx};
        }
        // Bundle: <=4 SAME-LAYER gates with independent masks (same-layer
        // conjugated gates have pairwise Pauli-parity 0 => flip stays 0);
        // pads prefer bits outside the bundle's row union (clean => flip 0).
        M.nbundles = 0;
        int s = 0;
        while (s < nsel && M.nbundles < 24) {
            BundleMeta& B = M.bd[M.nbundles++];
            for (int j = 0; j < 4; ++j) {
                B.gidx[j] = 0xFF; B.row[j] = 0; B.flip[j] = 0; B.nl[j] = 0;
            }
            uint16_t red[4], om[4]; int pv[4]; int nsl = 0;
            const int lay = ls[s].gidx >> 4;
            while (nsl < 4 && s < nsel && (ls[s].gidx >> 4) == lay) {
                uint16_t r0 = ls[s].m;
                for (int j = 0; j < nsl; ++j)
                    if ((r0 >> pv[j]) & 1) r0 ^= red[j];
                if (!r0) break;    // dependent -> close bundle
                pv[nsl] = 31 - __builtin_clz((unsigned)r0);
                red[nsl] = r0; om[nsl] = ls[s].m;
                B.gidx[nsl] = ls[s].gidx; B.row[nsl] = ls[s].r; B.nl[nsl] = ls[s].nl;
                ++nsl; ++s;
            }
            uint16_t rowU = 0;
            for (int j = 0; j < nsl; ++j) rowU |= B.row[j];
            for (int pass2 = 0; pass2 < 2 && nsl < 4; ++pass2) {
                for (int b = 11; b >= 0 && nsl < 4; --b) {
                    if (pass2 == 0 && ((rowU >> b) & 1)) continue;  // prefer clean
                    uint16_t r0 = (uint16_t)(1u << b);
                    for (int j = 0; j < nsl; ++j)
                        if ((r0 >> pv[j]) & 1) r0 ^= red[j];
                    if (!r0) continue;
                    pv[nsl] = 31 - __builtin_clz((unsigned)r0);
                    red[nsl] = r0; om[nsl] = (uint16_t)(1u << b);
                    ++nsl;
                }
            }
            for (int tt = 0; tt < 16; ++tt) {
                uint16_t v = 0;
                for (int j = 0; j < 4; ++j) if ((tt >> j) & 1) v ^= om[j];
                B.voff[tt] = v;
            }
            for (int j = 0; j < 4; ++j) {
                if (B.gidx[j] == 0xFF) continue;
                uint16_t f = 0;
                for (int tt = 0; tt < 16; ++tt)
                    if (__builtin_parity((unsigned)(B.voff[tt] & B.row[j])))
                        f |= (uint16_t)(1u << tt);
                B.flip[j] = f;
            }
            for (int a2 = 0; a2 < 4; ++a2)
                for (int b2 = a2 + 1; b2 < 4; ++b2)
                    if (pv[b2] < pv[a2]) { int tt = pv[a2]; pv[a2] = pv[b2]; pv[b2] = tt; }
            for (int j = 0; j < 4; ++j) B.piv[j] = (uint8_t)pv[j];
        }
        {   // measurement masks (used only if this pass is last)
            uint16_t r = 0; uint8_t nl = 0;
            for (int w = 0; w < 16; ++w)
                if (((Rmeas >> w) & 1) && packedOfWire[w] >= 0)
                    r |= (uint16_t)(1u << packedOfWire[w]);
            for (int k = 0; k < 4; ++k)
                if ((Rmeas >> gw[k]) & 1) nl |= (uint8_t)(1u << k);
            M.meas_row = r; M.meas_nl = nl;
        }
    }

    for (int g = 0; g < ngroups; ++g) {
        const float* Xg = X + (size_t)g * group * 16;
        float* og = out + (size_t)g * group;
        dim3 grid((unsigned)(group << 4));
        for (int p = 0; p < np; ++p) {
            int mode = (p == 0) ? 0 : ((p == np - 1) ? 2 : 1);
            if (mode == 0)
                pass_kernel<0><<<grid, dim3(256), 0, stream>>>(Xg, Wt, Bs, state, og, pms[p]);
            else if (mode == 1)
                pass_kernel<1><<<grid, dim3(256), 0, stream>>>(Xg, Wt, Bs, state, og, pms[p]);
            else
                pass_kernel<2><<<grid, dim3(256), 0, stream>>>(Xg, Wt, Bs, state, og, pms[p]);
        }
    }

    (void)in_sizes; (void)n_in; (void)out_size; (void)ws_size;
}